// Round 1
// baseline (4507.995 us; speedup 1.0000x reference)
//
#include <hip/hip_runtime.h>
#include <hip/hip_bf16.h>
#include <math.h>

// ---------------------------------------------------------------------------
// LSTM text classifier forward, MI355X/gfx950.
//   x   [64,512] i32 tokens; emb [50000,256] f32; W [256,1024] f32;
//   U   [256,1024] f32; b [1024] f32; Wd [256,20] f32; bd [20] f32
//   out = softmax(h_T @ Wd + bd)  [64,20] f32
//
// Phases:
//   1) pack_weights: W,U f32 -> bf16 in MFMA B-fragment order (one 16B
//      dwordx4 per lane per fragment at use time).
//   2) xz_gemm: xz[t][b][:] = emb[x[b,t]] @ W + b   (bf16 MFMA, fp32 acc,
//      stored bf16, t-major so the recurrence reads contiguous slabs).
//   3) lstm_seq: 4 workgroups x 16 batches, 8 waves each, sync-free across
//      WGs (recurrence entirely inside one CU). U K-steps 0..3 live in
//      registers (128 VGPR/wave), K-steps 4..7 streamed from L2 each step.
//      h kept bf16 in LDS (A-fragment friendly), c fp32 in registers.
//   4) head: dense 256->20 + softmax, one block per batch row.
//
// MFMA 16x16x32 bf16 layouts (verified per guide m89/m91):
//   A[m][k]: m = lane&15, k = (lane>>4)*8 + j   (j=0..7, 8 bf16 = 4 VGPR)
//   B[k][n]: n = lane&15, k = (lane>>4)*8 + j
//   C/D:     col = lane&15, row = (lane>>4)*4 + reg
// ---------------------------------------------------------------------------

typedef __bf16 bf16_t;
typedef bf16_t bf16x8 __attribute__((ext_vector_type(8)));
typedef float  f32x4  __attribute__((ext_vector_type(4)));

#define T_SZ 512
#define B_SZ 64
#define D_EMB 256
#define HID 256
#define G4 1024   // 4*HID
#define NCLS 20

// workspace layout (bytes)
#define WS_UPACK 0u
#define WS_WPACK (512u * 1024u)
#define WS_HFIN  (1024u * 1024u)
#define WS_XZ    (2u * 1024u * 1024u)
// total required: 2 MB + 512*64*1024*2 = 66 MB

// ---------------------------------------------------------------------------
// Pack W and U (f32 [256][1024]) into bf16 B-fragment order:
// frag index f = (ntile*8 + kstep)*64 + lane ; element j = 0..7
// value = M[kstep*32 + (lane>>4)*8 + j][ntile*16 + (lane&15)]
// ---------------------------------------------------------------------------
__global__ void pack_weights(const float* __restrict__ W, const float* __restrict__ U,
                             bf16_t* __restrict__ Wp, bf16_t* __restrict__ Up) {
    int tid  = blockIdx.x * blockDim.x + threadIdx.x;   // 0..262143
    int j    = tid & 7;
    int lane = (tid >> 3) & 63;
    int ks   = (tid >> 9) & 7;
    int nt   = tid >> 12;                               // 0..63
    int row  = ks * 32 + ((lane >> 4) << 3) + j;        // 0..255
    int col  = nt * 16 + (lane & 15);                   // 0..1023
    Wp[tid] = (bf16_t)W[row * G4 + col];
    Up[tid] = (bf16_t)U[row * G4 + col];
}

// ---------------------------------------------------------------------------
// Phase A: xz[t*64+b][:] = emb[x[b,t]] @ W + bias, stored bf16 t-major.
// Grid: 4096 blocks (512 t-tiles x 8 n-blocks of 128 cols), 256 thr = 4 waves.
// Wave w handles batches [16w,16w+16), all 8 of the block's N-tiles.
// A-fragments gathered straight from emb (fp32 -> bf16 in-register, no LDS).
// B-fragments read directly from packed W (L2-resident, 512 KB).
// ---------------------------------------------------------------------------
__global__ __launch_bounds__(256) void xz_gemm(const int* __restrict__ x,
                                               const float* __restrict__ emb,
                                               const bf16_t* __restrict__ Wp,
                                               const float* __restrict__ bias,
                                               bf16_t* __restrict__ xz) {
    int nb   = blockIdx.x & 7;    // N block: cols [nb*128, nb*128+128)
    int t    = blockIdx.x >> 3;   // timestep == M-tile of 64 rows (batches)
    int w    = threadIdx.x >> 6;
    int lane = threadIdx.x & 63;
    int l15  = lane & 15;
    int quad = lane >> 4;

    // A fragments: 8 K-steps for this wave's 16 batch rows
    int b_row = w * 16 + l15;
    int tok   = x[b_row * T_SZ + t];
    const float* erow = emb + (size_t)tok * D_EMB;

    bf16x8 afrag[8];
#pragma unroll
    for (int ks = 0; ks < 8; ks++) {
        const float4* p = (const float4*)(erow + ks * 32 + quad * 8);
        float4 v0 = p[0], v1 = p[1];
        bf16x8 a;
        a[0] = (bf16_t)v0.x; a[1] = (bf16_t)v0.y; a[2] = (bf16_t)v0.z; a[3] = (bf16_t)v0.w;
        a[4] = (bf16_t)v1.x; a[5] = (bf16_t)v1.y; a[6] = (bf16_t)v1.z; a[7] = (bf16_t)v1.w;
        afrag[ks] = a;
    }

    const bf16x8* Wf = (const bf16x8*)Wp;   // fragment-indexed view

#pragma unroll
    for (int nt = 0; nt < 8; nt++) {
        int ntg = nb * 8 + nt;
        float bv = bias[ntg * 16 + l15];          // col-dependent only
        f32x4 acc = {bv, bv, bv, bv};
        const bf16x8* bp = Wf + (size_t)(ntg * 8) * 64 + lane;
#pragma unroll
        for (int ks = 0; ks < 8; ks++) {
            bf16x8 bfrag = bp[ks * 64];
            acc = __builtin_amdgcn_mfma_f32_16x16x32_bf16(afrag[ks], bfrag, acc, 0, 0, 0);
        }
#pragma unroll
        for (int r = 0; r < 4; r++) {
            int brow = w * 16 + quad * 4 + r;     // C/D row = batch
            xz[((size_t)t * 64 + brow) * G4 + ntg * 16 + l15] = (bf16_t)acc[r];
        }
    }
}

__device__ __forceinline__ float sigmoid_f(float z) {
    return 1.0f / (1.0f + __expf(-z));   // saturates correctly via inf
}
__device__ __forceinline__ float tanh_f(float z) {
    float e = __expf(2.0f * z);          // tanh = 1 - 2/(e^{2z}+1); inf-safe
    return 1.0f - 2.0f / (e + 1.0f);
}

// ---------------------------------------------------------------------------
// Phase B: the serial recurrence. Grid: 4 blocks x 512 thr (8 waves).
// Block g owns batches [16g,16g+16) for all 512 steps -> no inter-WG sync.
// Wave w owns hidden tiles {2w,2w+1} (units [32w,32w+32)), i.e. z-tiles
// {G*16+2w+s : G=0..3 gates i,f,g,o ; s=0,1} -> i/f/g/o for a given unit all
// land in the same lane; c_new/h_new computed entirely in-register.
// U frags: K-steps 0..3 preloaded in registers (32 frags = 128 VGPR),
// K-steps 4..7 streamed from L2 each step (256 KB/CU/step).
// ---------------------------------------------------------------------------
__global__ __launch_bounds__(512, 2) void lstm_seq(const bf16_t* __restrict__ xz,
                                                   const bf16_t* __restrict__ Up,
                                                   float* __restrict__ hfin) {
    // +8 bf16 pad (16 B) per row: rotates LDS banks across batch rows and
    // keeps 16 B alignment for b128 A-fragment reads.
    __shared__ __align__(16) bf16_t h_lds[16][264];

    int g    = blockIdx.x;
    int w    = threadIdx.x >> 6;
    int lane = threadIdx.x & 63;
    int l15  = lane & 15;
    int quad = lane >> 4;

    for (int i = threadIdx.x; i < 16 * 264; i += 512)
        (&h_lds[0][0])[i] = (bf16_t)0.0f;   // h0 = 0

    const bf16x8* Uf = (const bf16x8*)Up + lane;   // lane-offset fragment view

    // Register-resident U: K-steps 0..3 of this wave's 8 z-tiles
    bf16x8 ureg[4][2][4];
#pragma unroll
    for (int G = 0; G < 4; G++)
#pragma unroll
        for (int s = 0; s < 2; s++) {
            int nt = G * 16 + 2 * w + s;
#pragma unroll
            for (int ks = 0; ks < 4; ks++)
                ureg[G][s][ks] = Uf[(nt * 8 + ks) * 64];
        }

    float cst[2][4];   // c state: fp32, [s][reg] -> unit (2w+s)*16+l15, batch quad*4+r
#pragma unroll
    for (int s = 0; s < 2; s++)
#pragma unroll
        for (int r = 0; r < 4; r++) cst[s][r] = 0.0f;

    __syncthreads();

    for (int t = 0; t < T_SZ; t++) {
        // A fragments for this step's h (batch m = l15, unit k)
        bf16x8 af[8];
#pragma unroll
        for (int ks = 0; ks < 8; ks++)
            af[ks] = *(const bf16x8*)&h_lds[l15][ks * 32 + quad * 8];

        __syncthreads();   // all waves done reading h_t

        const bf16_t* xzt = xz + ((size_t)t * 64 + g * 16 + quad * 4) * G4 + l15;

        f32x4 acc[4][2];
#pragma unroll
        for (int G = 0; G < 4; G++)
#pragma unroll
            for (int s = 0; s < 2; s++) {
                int nt     = G * 16 + 2 * w + s;
                int coloff = G * 256 + (2 * w + s) * 16;
                f32x4 a;
#pragma unroll
                for (int r = 0; r < 4; r++) a[r] = (float)xzt[r * G4 + coloff];
#pragma unroll
                for (int ks = 0; ks < 4; ks++)
                    a = __builtin_amdgcn_mfma_f32_16x16x32_bf16(af[ks], ureg[G][s][ks], a, 0, 0, 0);
#pragma unroll
                for (int ks = 4; ks < 8; ks++) {
                    bf16x8 uf = Uf[(nt * 8 + ks) * 64];   // streamed half of U
                    a = __builtin_amdgcn_mfma_f32_16x16x32_bf16(af[ks], uf, a, 0, 0, 0);
                }
                acc[G][s] = a;
            }

        // gates + state update, all in-lane (i,f,g,o share (s,r) slots)
#pragma unroll
        for (int s = 0; s < 2; s++)
#pragma unroll
            for (int r = 0; r < 4; r++) {
                float ig = sigmoid_f(acc[0][s][r]);
                float fg = sigmoid_f(acc[1][s][r]);
                float gg = tanh_f(acc[2][s][r]);
                float og = sigmoid_f(acc[3][s][r]);
                float cn = fg * cst[s][r] + ig * gg;
                cst[s][r] = cn;
                float hn = og * tanh_f(cn);
                h_lds[quad * 4 + r][(2 * w + s) * 16 + l15] = (bf16_t)hn;
                if (t == T_SZ - 1)
                    hfin[(g * 16 + quad * 4 + r) * HID + w * 32 + s * 16 + l15] = hn;
            }

        __syncthreads();   // h_{t+1} visible before next step's reads
    }
}

// ---------------------------------------------------------------------------
// Phase C: logits = h_T @ Wd + bd; softmax. One block per batch row.
// ---------------------------------------------------------------------------
__global__ void head(const float* __restrict__ hfin, const float* __restrict__ Wd,
                     const float* __restrict__ bd, float* __restrict__ out) {
    __shared__ float hrow[HID];
    __shared__ float lg[32];
    __shared__ float ex[32];
    int b = blockIdx.x, tid = threadIdx.x;   // 64 threads
    for (int i = tid; i < HID; i += 64) hrow[i] = hfin[b * HID + i];
    __syncthreads();
    if (tid < NCLS) {
        float acc = bd[tid];
        for (int k = 0; k < HID; k++) acc = fmaf(hrow[k], Wd[k * NCLS + tid], acc);
        lg[tid] = acc;
    }
    __syncthreads();
    if (tid < NCLS) {
        float m = -1e30f;
        for (int jj = 0; jj < NCLS; jj++) m = fmaxf(m, lg[jj]);
        ex[tid] = __expf(lg[tid] - m);
    }
    __syncthreads();
    if (tid < NCLS) {
        float sden = 0.0f;
        for (int jj = 0; jj < NCLS; jj++) sden += ex[jj];
        out[b * NCLS + tid] = ex[tid] / sden;
    }
}

// ---------------------------------------------------------------------------
extern "C" void kernel_launch(void* const* d_in, const int* in_sizes, int n_in,
                              void* d_out, int out_size, void* d_ws, size_t ws_size,
                              hipStream_t stream) {
    const int*   x    = (const int*)d_in[0];
    const float* emb  = (const float*)d_in[1];
    const float* W    = (const float*)d_in[2];
    const float* U    = (const float*)d_in[3];
    const float* bias = (const float*)d_in[4];
    const float* Wd   = (const float*)d_in[5];
    const float* bd   = (const float*)d_in[6];
    float* out = (float*)d_out;

    char* ws = (char*)d_ws;
    bf16_t* Up = (bf16_t*)(ws + WS_UPACK);
    bf16_t* Wp = (bf16_t*)(ws + WS_WPACK);
    float*  hf = (float*)(ws + WS_HFIN);
    bf16_t* xz = (bf16_t*)(ws + WS_XZ);

    pack_weights<<<dim3(1024), dim3(256), 0, stream>>>(W, U, Wp, Up);
    xz_gemm<<<dim3(4096), dim3(256), 0, stream>>>(x, emb, Wp, bias, xz);
    lstm_seq<<<dim3(4), dim3(512), 0, stream>>>(xz, Up, hf);
    head<<<dim3(64), dim3(64), 0, stream>>>(hf, Wd, bd, out);
}

// Round 2
// 1998.367 us; speedup vs baseline: 2.2558x; 2.2558x over previous
//
#include <hip/hip_runtime.h>
#include <hip/hip_bf16.h>
#include <math.h>

// ---------------------------------------------------------------------------
// LSTM text classifier forward, MI355X/gfx950.  Round 2.
//
// R1 post-mortem: VGPR_Count=128 => compiler sank the "register-resident"
// half of U into the t-loop; full 512 KB of U streamed from L2 every step
// (8.5us/step). Root cause: U (512KB bf16) == entire CU register file.
//
// R2 structure: 16 blocks = 4 batch-groups x 4 unit-slices.
//   - Each block: 16 batches x 64 output units. U-slice = 256x256 bf16 =
//     128 KB = 64 VGPRs/wave (8 waves) -> genuinely register-resident.
//   - Per step: 128 MFMAs/block, then exchange 2 KB h-slices among the 4
//     sibling blocks of the batch group via agent-scope (L3-coherent)
//     atomics: relaxed dword stores for data + one release atomicAdd /
//     acquire spin per block per step. Double-buffered slots; per-step
//     counters zeroed by init kernel => no ABA, no deadlock (16 blocks
//     are trivially co-resident on 256 CUs).
//   - xz re-laid out in C-fragment order: 1x 8B load/lane/tile, prefetched
//     one step ahead (was 32 scalar bf16 loads/lane).
//
// MFMA 16x16x32 bf16 layouts (m89/m91):
//   A[m][k]: m=lane&15, k=(lane>>4)*8+j      B[k][n]: n=lane&15, same k
//   C/D:     col=lane&15, row=(lane>>4)*4+reg
// ---------------------------------------------------------------------------

typedef __bf16 bf16_t;
typedef bf16_t bf16x8 __attribute__((ext_vector_type(8)));
typedef bf16_t bf16x4 __attribute__((ext_vector_type(4)));
typedef float  f32x4  __attribute__((ext_vector_type(4)));

#define T_SZ 512
#define HID 256
#define G4 1024
#define NCLS 20

// workspace layout (bytes)
#define WS_UPACK 0u
#define WS_WPACK (512u * 1024u)
#define WS_HFIN  (1024u * 1024u)                  // 64 KB
#define WS_CNT   (1024u * 1024u + 64u * 1024u)    // 8 KB  (512*4 uints)
#define WS_HEXCH (1024u * 1024u + 128u * 1024u)   // 64 KB (2*16*512 dwords)
#define WS_XZ    (2u * 1024u * 1024u)             // 64 MB
// total: 66 MB

// ---------------------------------------------------------------------------
// Pack W and U (f32 [256][1024]) into bf16 B-fragment order:
// frag f = (ntile*8 + kstep)*64 + lane ; element j=0..7
// value = M[kstep*32 + (lane>>4)*8 + j][ntile*16 + (lane&15)]
// ---------------------------------------------------------------------------
__global__ void pack_weights(const float* __restrict__ W, const float* __restrict__ U,
                             bf16_t* __restrict__ Wp, bf16_t* __restrict__ Up) {
    int tid  = blockIdx.x * blockDim.x + threadIdx.x;   // 0..262143
    int j    = tid & 7;
    int lane = (tid >> 3) & 63;
    int ks   = (tid >> 9) & 7;
    int nt   = tid >> 12;
    int row  = ks * 32 + ((lane >> 4) << 3) + j;
    int col  = nt * 16 + (lane & 15);
    Wp[tid] = (bf16_t)W[row * G4 + col];
    Up[tid] = (bf16_t)U[row * G4 + col];
}

// ---------------------------------------------------------------------------
// Phase A: xz = emb[x] @ W + bias, stored bf16 in C-fragment order:
//   xz2[(((t*4 + bchunk)*64 + ntile)*64 + lane)] = bf16x4 {r=0..3}
// where value[r] = z[batch = bchunk*16 + (lane>>4)*4 + r][col = ntile*16 + (lane&15)]
// Grid: 4096 blocks (512 t x 8 n-blocks), 256 thr = 4 waves; wave w = bchunk w.
// ---------------------------------------------------------------------------
__global__ __launch_bounds__(256) void xz_gemm(const int* __restrict__ x,
                                               const float* __restrict__ emb,
                                               const bf16_t* __restrict__ Wp,
                                               const float* __restrict__ bias,
                                               bf16x4* __restrict__ xz2) {
    int nb   = blockIdx.x & 7;
    int t    = blockIdx.x >> 3;
    int w    = threadIdx.x >> 6;
    int lane = threadIdx.x & 63;
    int l15  = lane & 15;
    int quad = lane >> 4;

    int b_row = w * 16 + l15;
    int tok   = x[b_row * T_SZ + t];
    const float* erow = emb + (size_t)tok * 256;

    bf16x8 afrag[8];
#pragma unroll
    for (int ks = 0; ks < 8; ks++) {
        const float4* p = (const float4*)(erow + ks * 32 + quad * 8);
        float4 v0 = p[0], v1 = p[1];
        bf16x8 a;
        a[0] = (bf16_t)v0.x; a[1] = (bf16_t)v0.y; a[2] = (bf16_t)v0.z; a[3] = (bf16_t)v0.w;
        a[4] = (bf16_t)v1.x; a[5] = (bf16_t)v1.y; a[6] = (bf16_t)v1.z; a[7] = (bf16_t)v1.w;
        afrag[ks] = a;
    }

    const bf16x8* Wf = (const bf16x8*)Wp;

#pragma unroll
    for (int nt = 0; nt < 8; nt++) {
        int ntg = nb * 8 + nt;
        float bv = bias[ntg * 16 + l15];
        f32x4 acc = {bv, bv, bv, bv};
        const bf16x8* bp = Wf + (size_t)(ntg * 8) * 64 + lane;
#pragma unroll
        for (int ks = 0; ks < 8; ks++) {
            bf16x8 bfrag = bp[ks * 64];
            acc = __builtin_amdgcn_mfma_f32_16x16x32_bf16(afrag[ks], bfrag, acc, 0, 0, 0);
        }
        bf16x4 hv;
#pragma unroll
        for (int r = 0; r < 4; r++) hv[r] = (bf16_t)acc[r];
        xz2[((size_t)(t * 4 + w) * 64 + ntg) * 64 + lane] = hv;
    }
}

__device__ __forceinline__ float sigmoid_f(float z) {
    return 1.0f / (1.0f + __expf(-z));
}
__device__ __forceinline__ float tanh_f(float z) {
    float e = __expf(2.0f * z);
    return 1.0f - 2.0f / (e + 1.0f);
}
__device__ __forceinline__ unsigned pack2(float a, float b) {
    unsigned short xs = __builtin_bit_cast(unsigned short, (bf16_t)a);
    unsigned short ys = __builtin_bit_cast(unsigned short, (bf16_t)b);
    return (unsigned)xs | ((unsigned)ys << 16);
}
__device__ __forceinline__ bf16_t unpk_lo(unsigned v) {
    return __builtin_bit_cast(bf16_t, (unsigned short)(v & 0xffffu));
}
__device__ __forceinline__ bf16_t unpk_hi(unsigned v) {
    return __builtin_bit_cast(bf16_t, (unsigned short)(v >> 16));
}

__global__ void init_flags(unsigned* __restrict__ cnt) {
    int i = blockIdx.x * 256 + threadIdx.x;
    if (i < T_SZ * 4) cnt[i] = 0u;
}

// ---------------------------------------------------------------------------
// Phase B: recurrence. Grid: 16 blocks x 512 thr (8 waves).
// block = g*4 + u : batch group g (batches 16g..16g+16), unit slice u
// (units 64u..64u+64 => z-tiles {G*16 + u*4 + ut}).
// Wave w computes gate G=w>>1 for unit-tiles {2(w&1), 2(w&1)+1} (2 z-tiles,
// 16 MFMAs/step), applies its gate's activation, shares via LDS.
// Waves 0..3 combine gates for unit-tile w, update c (regs), produce h,
// publish the 2 KB h-slice via agent-scope relaxed atomic dwords + a
// release atomicAdd on cnt[t*4+g]; all blocks of the group acquire-spin
// to 4, then pull the 3 sibling slices into h_lds for the next A-frags.
// ---------------------------------------------------------------------------
__global__ __launch_bounds__(512, 2) void lstm_seq16(const bf16x4* __restrict__ xz2,
                                                     const bf16_t* __restrict__ Up,
                                                     unsigned* __restrict__ cnt,
                                                     unsigned* __restrict__ hexch,
                                                     float* __restrict__ hfin) {
    __shared__ __align__(16) bf16_t h_lds[16][264];     // [batch][unit(+pad)]
    __shared__ float zlds[4][4][16][17];                // [gate][ut][u16][b16+1]

    const int u    = blockIdx.x & 3;
    const int g    = blockIdx.x >> 2;
    const int w    = threadIdx.x >> 6;
    const int lane = threadIdx.x & 63;
    const int l15  = lane & 15;
    const int quad = lane >> 4;
    const int Gg   = w >> 1;              // this wave's gate
    const int ut0  = (w & 1) * 2;         // first of its 2 unit-tiles

    const int ntgA = Gg * 16 + u * 4 + ut0;
    const int ntgB = ntgA + 1;

    // register-resident U-slice: 2 z-tiles x 8 k-steps = 64 VGPRs
    const bf16x8* Uf = (const bf16x8*)Up + lane;
    bf16x8 ureg[2][8];
#pragma unroll
    for (int ks = 0; ks < 8; ks++) {
        ureg[0][ks] = Uf[(ntgA * 8 + ks) * 64];
        ureg[1][ks] = Uf[(ntgB * 8 + ks) * 64];
    }

    f32x4 cst = {0.f, 0.f, 0.f, 0.f};     // c-state (waves 0..3)

    bf16x8 af[8];                          // A-frags; h0 = 0
#pragma unroll
    for (int ks = 0; ks < 8; ks++)
#pragma unroll
        for (int j = 0; j < 8; j++) af[ks][j] = (bf16_t)0.0f;

    // xz prefetch for t=0
    bf16x4 xzv0 = xz2[((size_t)(0 * 4 + g) * 64 + ntgA) * 64 + lane];
    bf16x4 xzv1 = xz2[((size_t)(0 * 4 + g) * 64 + ntgB) * 64 + lane];

    for (int t = 0; t < T_SZ; t++) {
        f32x4 a0 = {(float)xzv0[0], (float)xzv0[1], (float)xzv0[2], (float)xzv0[3]};
        f32x4 a1 = {(float)xzv1[0], (float)xzv1[1], (float)xzv1[2], (float)xzv1[3]};
#pragma unroll
        for (int ks = 0; ks < 8; ks++)
            a0 = __builtin_amdgcn_mfma_f32_16x16x32_bf16(af[ks], ureg[0][ks], a0, 0, 0, 0);
#pragma unroll
        for (int ks = 0; ks < 8; ks++)
            a1 = __builtin_amdgcn_mfma_f32_16x16x32_bf16(af[ks], ureg[1][ks], a1, 0, 0, 0);

        if (t + 1 < T_SZ) {   // prefetch next step's xz (no dependency)
            xzv0 = xz2[((size_t)((t + 1) * 4 + g) * 64 + ntgA) * 64 + lane];
            xzv1 = xz2[((size_t)((t + 1) * 4 + g) * 64 + ntgB) * 64 + lane];
        }

        // in-wave activation (gate-uniform per wave), share via LDS
        float act0[4], act1[4];
        if (Gg == 2) {
#pragma unroll
            for (int r = 0; r < 4; r++) { act0[r] = tanh_f(a0[r]); act1[r] = tanh_f(a1[r]); }
        } else {
#pragma unroll
            for (int r = 0; r < 4; r++) { act0[r] = sigmoid_f(a0[r]); act1[r] = sigmoid_f(a1[r]); }
        }
#pragma unroll
        for (int r = 0; r < 4; r++) {
            zlds[Gg][ut0][l15][quad * 4 + r]     = act0[r];
            zlds[Gg][ut0 + 1][l15][quad * 4 + r] = act1[r];
        }
        __syncthreads();   // B1: zlds complete

        if (w < 4) {       // combine gates for unit-tile w; batches quad*4+r
            float hv[4];
#pragma unroll
            for (int r = 0; r < 4; r++) {
                float ig = zlds[0][w][l15][quad * 4 + r];
                float fg = zlds[1][w][l15][quad * 4 + r];
                float gg = zlds[2][w][l15][quad * 4 + r];
                float og = zlds[3][w][l15][quad * 4 + r];
                float cn = fg * cst[r] + ig * gg;
                cst[r] = cn;
                hv[r] = og * tanh_f(cn);
            }
            int ucol = u * 64 + w * 16 + l15;   // global unit
            if (t < T_SZ - 1) {
#pragma unroll
                for (int r = 0; r < 4; r++)
                    h_lds[quad * 4 + r][ucol] = (bf16_t)hv[r];
                unsigned dw0 = pack2(hv[0], hv[1]);
                unsigned dw1 = pack2(hv[2], hv[3]);
                unsigned sbase = (unsigned)(((t & 1) * 16 + blockIdx.x) * 512);
                unsigned di = (unsigned)(w * 16 + l15) * 8u + (unsigned)(quad * 2);
                __hip_atomic_store(&hexch[sbase + di],     dw0, __ATOMIC_RELAXED, __HIP_MEMORY_SCOPE_AGENT);
                __hip_atomic_store(&hexch[sbase + di + 1], dw1, __ATOMIC_RELAXED, __HIP_MEMORY_SCOPE_AGENT);
            } else {
#pragma unroll
                for (int r = 0; r < 4; r++)
                    hfin[(g * 16 + quad * 4 + r) * HID + ucol] = hv[r];
            }
        }
        if (t == T_SZ - 1) break;   // uniform exit; no barrier mismatch

        __syncthreads();   // B2: all stores drained (vmcnt(0) before barrier)

        if (threadIdx.x == 0) {
            unsigned* c = cnt + (t * 4 + g);
            __hip_atomic_fetch_add(c, 1u, __ATOMIC_RELEASE, __HIP_MEMORY_SCOPE_AGENT);
            while (__hip_atomic_load(c, __ATOMIC_RELAXED, __HIP_MEMORY_SCOPE_AGENT) < 4u) {}
            (void)__hip_atomic_load(c, __ATOMIC_ACQUIRE, __HIP_MEMORY_SCOPE_AGENT);
        }
        __syncthreads();   // B3: group data visible

        // pull 3 sibling h-slices into h_lds (each thread: dword tid of each slot)
        {
            unsigned pbase = (unsigned)((t & 1) * 16 + g * 4);
            int ul = threadIdx.x >> 3;          // unit within slice
            int bp = threadIdx.x & 7;           // batch pair
#pragma unroll
            for (int n = 1; n < 4; n++) {
                int unb = (u + n) & 3;
                unsigned dval = __hip_atomic_load(&hexch[(pbase + unb) * 512 + threadIdx.x],
                                                  __ATOMIC_RELAXED, __HIP_MEMORY_SCOPE_AGENT);
                h_lds[2 * bp][unb * 64 + ul]     = unpk_lo(dval);
                h_lds[2 * bp + 1][unb * 64 + ul] = unpk_hi(dval);
            }
        }
        __syncthreads();   // B4: h_lds complete

        // A-frags for next step
#pragma unroll
        for (int ks = 0; ks < 8; ks++)
            af[ks] = *(const bf16x8*)&h_lds[l15][ks * 32 + quad * 8];
    }
}

// ---------------------------------------------------------------------------
// Phase C: logits = h_T @ Wd + bd; softmax. One block per batch row.
// ---------------------------------------------------------------------------
__global__ void head(const float* __restrict__ hfin, const float* __restrict__ Wd,
                     const float* __restrict__ bd, float* __restrict__ out) {
    __shared__ float hrow[HID];
    __shared__ float lg[32];
    __shared__ float ex[32];
    int b = blockIdx.x, tid = threadIdx.x;   // 64 threads
    for (int i = tid; i < HID; i += 64) hrow[i] = hfin[b * HID + i];
    __syncthreads();
    if (tid < NCLS) {
        float acc = bd[tid];
        for (int k = 0; k < HID; k++) acc = fmaf(hrow[k], Wd[k * NCLS + tid], acc);
        lg[tid] = acc;
    }
    __syncthreads();
    if (tid < NCLS) {
        float m = -1e30f;
        for (int jj = 0; jj < NCLS; jj++) m = fmaxf(m, lg[jj]);
        ex[tid] = __expf(lg[tid] - m);
    }
    __syncthreads();
    if (tid < NCLS) {
        float sden = 0.0f;
        for (int jj = 0; jj < NCLS; jj++) sden += ex[jj];
        out[b * NCLS + tid] = ex[tid] / sden;
    }
}

// ---------------------------------------------------------------------------
extern "C" void kernel_launch(void* const* d_in, const int* in_sizes, int n_in,
                              void* d_out, int out_size, void* d_ws, size_t ws_size,
                              hipStream_t stream) {
    const int*   x    = (const int*)d_in[0];
    const float* emb  = (const float*)d_in[1];
    const float* W    = (const float*)d_in[2];
    const float* U    = (const float*)d_in[3];
    const float* bias = (const float*)d_in[4];
    const float* Wd   = (const float*)d_in[5];
    const float* bd   = (const float*)d_in[6];
    float* out = (float*)d_out;

    char* ws = (char*)d_ws;
    bf16_t*   Up    = (bf16_t*)(ws + WS_UPACK);
    bf16_t*   Wp    = (bf16_t*)(ws + WS_WPACK);
    float*    hf    = (float*)(ws + WS_HFIN);
    unsigned* cnt   = (unsigned*)(ws + WS_CNT);
    unsigned* hexch = (unsigned*)(ws + WS_HEXCH);
    bf16x4*   xz2   = (bf16x4*)(ws + WS_XZ);

    init_flags<<<dim3(8), dim3(256), 0, stream>>>(cnt);
    pack_weights<<<dim3(1024), dim3(256), 0, stream>>>(W, U, Wp, Up);
    xz_gemm<<<dim3(4096), dim3(256), 0, stream>>>(x, emb, Wp, bias, xz2);
    lstm_seq16<<<dim3(16), dim3(512), 0, stream>>>(xz2, Up, cnt, hexch, hf);
    head<<<dim3(64), dim3(64), 0, stream>>>(hf, Wd, bd, out);
}